// Round 5
// baseline (315.879 us; speedup 1.0000x reference)
//
#include <hip/hip_runtime.h>

typedef __attribute__((ext_vector_type(8))) short short8;
typedef __attribute__((ext_vector_type(4))) float f32x4;
typedef __attribute__((ext_vector_type(16))) float f32x16;

#define DEV static __device__ __forceinline__

DEV unsigned short f2bf(float f) {
  unsigned int u = __float_as_uint(f);
  u += 0x7fff + ((u >> 16) & 1);   // RNE
  return (unsigned short)(u >> 16);
}

DEV unsigned int cvtpk(float lo, float hi) {   // packed f32x2 -> bf16x2 (RNE)
  unsigned int r;
  asm("v_cvt_pk_bf16_f32 %0, %1, %2" : "=v"(r) : "v"(lo), "v"(hi));
  return r;
}

DEV f32x4 mfma16(short8 a, short8 b, f32x4 c) {
  return __builtin_amdgcn_mfma_f32_16x16x32_bf16(a, b, c, 0, 0, 0);
}

DEV f32x16 mfma32(short8 a, short8 b, f32x16 c) {
  return __builtin_amdgcn_mfma_f32_32x32x16_bf16(a, b, c, 0, 0, 0);
}

DEV void gl_lds16(const void* g, void* l) {
  __builtin_amdgcn_global_load_lds((const __attribute__((address_space(1))) void*)g,
                                   (__attribute__((address_space(3))) void*)l, 16, 0, 0);
}

// ---------------------------------------------------------------------------
// Convert Wq / Wk / Wv fp32 -> bf16 (wqb 1024x1024; wkvb 512x1024, k then v)
// ---------------------------------------------------------------------------
__global__ __launch_bounds__(256) void cvtB_kernel(const float* __restrict__ Wq,
                                                   const float* __restrict__ Wk,
                                                   const float* __restrict__ Wv,
                                                   unsigned short* __restrict__ wqb,
                                                   unsigned short* __restrict__ wkvb) {
  int id = blockIdx.x * 256 + threadIdx.x;   // 393216 threads x 4 elems
  int e = id * 4;
  float4 v;
  unsigned short* d;
  if (e < 1048576)      { v = *(const float4*)(Wq + e);             d = wqb + e; }
  else if (e < 1310720) { v = *(const float4*)(Wk + (e - 1048576)); d = wkvb + (e - 1048576); }
  else                  { v = *(const float4*)(Wv + (e - 1310720)); d = wkvb + 262144 + (e - 1310720); }
  uint2 pk;
  pk.x = cvtpk(v.x, v.y);
  pk.y = cvtpk(v.z, v.w);
  *(uint2*)d = pk;
}

// ---------------------------------------------------------------------------
// Wrp = Wr @ Wo  (2 x 1024)
// ---------------------------------------------------------------------------
__global__ __launch_bounds__(256) void wrp_partial(const float* __restrict__ Wr,
                                                   const float* __restrict__ Wo,
                                                   float* __restrict__ part) {
  int blk = blockIdx.x;
  int tid = threadIdx.x;
  float a0[4] = {0.f,0.f,0.f,0.f};
  float a1[4] = {0.f,0.f,0.f,0.f};
  int e0 = blk * 64;
  for (int e = e0; e < e0 + 64; e++) {
    float w0 = Wr[e];
    float w1 = Wr[1024 + e];
    #pragma unroll
    for (int j4 = 0; j4 < 4; j4++) {
      float wo = Wo[(size_t)e * 1024 + j4 * 256 + tid];
      a0[j4] += w0 * wo;
      a1[j4] += w1 * wo;
    }
  }
  #pragma unroll
  for (int j4 = 0; j4 < 4; j4++) {
    part[blk * 2048 + 0    + j4 * 256 + tid] = a0[j4];
    part[blk * 2048 + 1024 + j4 * 256 + tid] = a1[j4];
  }
}

__global__ __launch_bounds__(256) void wrp_reduce(const float* __restrict__ part,
                                                  float* __restrict__ Wrp) {
  int id = blockIdx.x * 256 + threadIdx.x;
  float s = 0.f;
  #pragma unroll
  for (int blk = 0; blk < 16; blk++) s += part[blk * 2048 + id];
  Wrp[id] = s;
}

// ---------------------------------------------------------------------------
// KV projection GEMM: C = h(fp32, 32768x1024) @ Wkv(bf16, 512x1024)^T
// BM=32 (grid 1024, 4 blocks/CU), BN=512 (full N -> h read ONCE), BK=16,
// mfma_f32_32x32x16_bf16. 4 waves, wave w owns cols w*128..+128 (4 frags).
// A: global->reg->cvt_pk (no LDS). B: global_load_lds, [512][16] bf16 linear
// (conflict-free at floor for 32x32 frag reads). Latency hidden by 4
// co-resident blocks per CU.
// Output: ok bf16 (B,KV,K,D), ov bf16 (B,KV,D,K) transposed.
// ---------------------------------------------------------------------------
__global__ __launch_bounds__(256, 4) void gemm_kv(const float* __restrict__ A,
                                                  const unsigned short* __restrict__ Bb,
                                                  unsigned short* __restrict__ ok,
                                                  unsigned short* __restrict__ ov) {
  __shared__ unsigned short Bs[2][8192];   // 2 x 16KB : [512 rows][16 k]

  int bid = blockIdx.x;
  int sw = (bid & 7) * 128 + (bid >> 3);   // XCD swizzle (1024 = 8*128)
  int m0 = sw * 32;

  int tid = threadIdx.x;
  int w = tid >> 6, l = tid & 63;
  int r31 = l & 31, ko = l >> 5;

  // A: lane covers row m0+r31, k-octet ko (8 fp32 = 2 float4)
  const float* ga = A + (size_t)(m0 + r31) * 1024 + ko * 8;
  // B staging: slot s = j*256+tid -> row s>>1, k-half s&1
  const unsigned short* gb = Bb + (size_t)(tid >> 1) * 1024 + (tid & 1) * 8;
  int ldsoff = tid * 16;                   // byte offset in buffer
  // B frag read: row n = w*128 + fc*32 + r31, byte n*32 + ko*16
  int brd = (w * 128 + r31) * 32 + ko * 16;

  f32x16 acc[4];
  #pragma unroll
  for (int j = 0; j < 4; j++) acc[j] = (f32x16)(0.f);

  float4 aA, aB, nA, nB;

  #define STAGEB(bufi, tt)                                                  \
    { const unsigned short* s0 = gb + (tt) * 16;                            \
      char* d0 = (char*)Bs[bufi] + ldsoff;                                  \
      gl_lds16(s0,          d0);                                            \
      gl_lds16(s0 + 131072, d0 + 4096);                                     \
      gl_lds16(s0 + 262144, d0 + 8192);                                     \
      gl_lds16(s0 + 393216, d0 + 12288); }

  STAGEB(0, 0);
  aA = *(const float4*)(ga);
  aB = *(const float4*)(ga + 4);
  nA = aA; nB = aB;
  __syncthreads();

  for (int t = 0; t < 64; t++) {
    int buf = t & 1;
    if (t + 1 < 64) {
      STAGEB(buf ^ 1, t + 1);
      nA = *(const float4*)(ga + (t + 1) * 16);
      nB = *(const float4*)(ga + (t + 1) * 16 + 4);
    }
    short8 bfr[4];
    #pragma unroll
    for (int fc = 0; fc < 4; fc++)
      bfr[fc] = *(const short8*)((char*)Bs[buf] + brd + fc * 1024);
    union { short8 s; unsigned int u[4]; } af;
    af.u[0] = cvtpk(aA.x, aA.y); af.u[1] = cvtpk(aA.z, aA.w);
    af.u[2] = cvtpk(aB.x, aB.y); af.u[3] = cvtpk(aB.z, aB.w);
    #pragma unroll
    for (int fc = 0; fc < 4; fc++)
      acc[fc] = mfma32(af.s, bfr[fc], acc[fc]);
    aA = nA; aB = nB;
    __syncthreads();
  }
  #undef STAGEB

  // epilogue: C/D layout col=lane&31 (-> n), row=(reg&3)+8*(reg>>2)+4*(lane>>5) (-> m)
  #pragma unroll
  for (int fc = 0; fc < 4; fc++) {
    int n = w * 128 + fc * 32 + r31;
    int kvv = n >> 6, d = n & 63;
    #pragma unroll
    for (int rg = 0; rg < 16; rg++) {
      int m = m0 + (rg & 3) + 8 * (rg >> 2) + 4 * ko;
      int bb = m >> 11, kk = m & 2047;
      unsigned short val = f2bf(acc[fc][rg]);
      if (kvv < 4)
        ok[((size_t)(bb * 4 + kvv) * 2048 + kk) * 64 + d] = val;           // (B,KV,K,D)
      else
        ov[((size_t)(bb * 4 + (kvv - 4)) * 64 + d) * 2048 + kk] = val;     // (B,KV,D,K)
    }
  }
}

// ---------------------------------------------------------------------------
// q projection GEMM (small): C = oq @ Wq^T, 128x128 tile, BK=32, 4-way K-split
// ---------------------------------------------------------------------------
__global__ __launch_bounds__(256) void gemm_q(const float* __restrict__ A,
                                              const unsigned short* __restrict__ Bb,
                                              float* __restrict__ of) {
  __shared__ unsigned short Asm[2][4096];
  __shared__ unsigned short Bsm[2][4096];

  int bid = blockIdx.x;
  int ksplit = bid >> 4;
  int m0 = ((bid >> 3) & 1) * 128;
  int n0 = (bid & 7) * 128;
  int t0 = ksplit * 8;
  constexpr int nt = 8;

  int tid = threadIdx.x;
  int w = tid >> 6, l = tid & 63;
  int l4 = l >> 4, l15 = l & 15;
  int wm = w >> 1, wn = w & 1;

  int ra = w * 32 + (l >> 1);
  int rx = (l >> 2) & 3;
  const float* ga = A + (size_t)(m0 + ra) * 1024 + t0 * 32 + (l & 1) * 16;
  int pw0 = (2 * (l & 1) + 0) ^ rx;
  int pw1 = (2 * (l & 1) + 1) ^ rx;
  int awb0 = ra * 64 + pw0 * 16;
  int awb1 = ra * 64 + pw1 * 16;

  int rb = w * 32 + (l >> 2);
  int cb = ((l & 3) ^ ((l >> 3) & 3)) * 8;
  const unsigned short* gb = Bb + (size_t)(n0 + rb) * 1024 + t0 * 32 + cb;

  int qsw = l4 ^ ((l15 >> 1) & 3);
  int arb = (wm * 64 + l15) * 64 + qsw * 16;
  int brb = (wn * 64 + l15) * 64 + qsw * 16;

  f32x4 acc[4][4];
  #pragma unroll
  for (int i = 0; i < 4; i++)
    #pragma unroll
    for (int j = 0; j < 4; j++) acc[i][j] = (f32x4)(0.f);

  float4 fa0, fa1, fa2, fa3;

  #define LOADA(tt)                                                        \
    { const float* gA = ga + (tt) * 32;                                    \
      fa0 = *(const float4*)(gA);                                          \
      fa1 = *(const float4*)(gA + 4);                                      \
      fa2 = *(const float4*)(gA + 8);                                      \
      fa3 = *(const float4*)(gA + 12); }

  #define WRITEA(bufi)                                                     \
    { union { short8 s; unsigned int u[4]; } t0u, t1u;                     \
      t0u.u[0] = cvtpk(fa0.x, fa0.y); t0u.u[1] = cvtpk(fa0.z, fa0.w);      \
      t0u.u[2] = cvtpk(fa1.x, fa1.y); t0u.u[3] = cvtpk(fa1.z, fa1.w);      \
      t1u.u[0] = cvtpk(fa2.x, fa2.y); t1u.u[1] = cvtpk(fa2.z, fa2.w);      \
      t1u.u[2] = cvtpk(fa3.x, fa3.y); t1u.u[3] = cvtpk(fa3.z, fa3.w);      \
      *(short8*)((char*)Asm[bufi] + awb0) = t0u.s;                         \
      *(short8*)((char*)Asm[bufi] + awb1) = t1u.s; }

  #define STAGEB(bufi, tt)                                                 \
    { char* lb = (char*)Bsm[bufi] + w * 2048;                              \
      const unsigned short* gB = gb + (tt) * 32;                           \
      gl_lds16(gB, lb);                                                    \
      gl_lds16(gB + 16384, lb + 1024); }

  LOADA(0);
  STAGEB(0, 0);
  WRITEA(0);
  __syncthreads();

  for (int t = 0; t < nt; t++) {
    int buf = t & 1;
    if (t + 1 < nt) {
      LOADA(t + 1);
      STAGEB(buf ^ 1, t + 1);
    }
    short8 af[4], bfg[4];
    #pragma unroll
    for (int i = 0; i < 4; i++)
      af[i] = *(const short8*)((char*)Asm[buf] + arb + i * 1024);
    #pragma unroll
    for (int j = 0; j < 4; j++)
      bfg[j] = *(const short8*)((char*)Bsm[buf] + brb + j * 1024);
    #pragma unroll
    for (int i = 0; i < 4; i++)
      #pragma unroll
      for (int j = 0; j < 4; j++)
        acc[i][j] = mfma16(af[i], bfg[j], acc[i][j]);
    if (t + 1 < nt) WRITEA(buf ^ 1);
    __syncthreads();
  }
  #undef LOADA
  #undef WRITEA
  #undef STAGEB

  float* o = of + (size_t)ksplit * 262144;
  #pragma unroll
  for (int i = 0; i < 4; i++)
    #pragma unroll
    for (int j = 0; j < 4; j++) {
      int n = n0 + wn * 64 + j * 16 + l15;
      #pragma unroll
      for (int r = 0; r < 4; r++) {
        int m = m0 + wm * 64 + i * 16 + l4 * 4 + r;
        o[(size_t)m * 1024 + n] = acc[i][j][r];
      }
    }
}

// ---------------------------------------------------------------------------
// Sum 4 K-split partials + RoPE + scale, write bf16 as (H, BIN, D)
// ---------------------------------------------------------------------------
__global__ __launch_bounds__(256) void rope_kernel(const float* __restrict__ qp,
                                                   const float* __restrict__ cosb,
                                                   const float* __restrict__ sinb,
                                                   unsigned short* __restrict__ qb) {
  int id = blockIdx.x * 256 + threadIdx.x;   // 262144
  int qrow = id >> 10, hd = id & 1023, hh = hd >> 6, d = hd & 63;
  int od = hh * 64 + ((d < 32) ? d + 32 : d - 32);
  float v = 0.f, o = 0.f;
  #pragma unroll
  for (int s4 = 0; s4 < 4; s4++) {
    v += qp[s4 * 262144 + qrow * 1024 + hd];
    o += qp[s4 * 262144 + qrow * 1024 + od];
  }
  if (d < 32) o = -o;
  float c = cosb[qrow * 64 + d];
  float s = sinb[qrow * 64 + d];
  float outv = (v * c + o * s) * 0.18033688011112042f;  // 0.125 * log2(e)
  qb[((size_t)hh * 256 + qrow) * 64 + d] = f2bf(outv);
}

// ---------------------------------------------------------------------------
// Flash attention, one block per (b, h, q-half). 4 waves x 32 q-rows.
// ---------------------------------------------------------------------------
__global__ __launch_bounds__(256) void attn_kernel(const unsigned short* __restrict__ qb,
                                                   const unsigned short* __restrict__ kb,
                                                   const unsigned short* __restrict__ vb,
                                                   const float* __restrict__ Wrp,
                                                   float* __restrict__ part) {
  __shared__ unsigned short Kt[2][4096];
  __shared__ unsigned short Vt[2][4096];
  __shared__ unsigned short Pl[4][2048];

  int bid = blockIdx.x;
  int vidx = (bid & 7) * 64 + (bid >> 3);     // XCD swizzle (512 = 8*64)
  int b = vidx >> 5, h = (vidx >> 1) & 15, qh = vidx & 1;
  int kvh = h >> 2;

  int tid = threadIdx.x;
  int w = tid >> 6, l = tid & 63;
  int l4 = l >> 4, l15 = l & 15;
  int q0 = qh * 128 + w * 32;

  const unsigned short* kg = kb + (size_t)(b * 4 + kvh) * 2048 * 64;
  const unsigned short* vg = vb + (size_t)(b * 4 + kvh) * 64 * 2048;

  short8 qf[2][2];
  #pragma unroll
  for (int fr = 0; fr < 2; fr++)
    #pragma unroll
    for (int ks = 0; ks < 2; ks++)
      qf[fr][ks] = *(const short8*)&qb[((size_t)h * 256 + q0 + fr * 16 + l15) * 64 + ks * 32 + l4 * 8];

  f32x4 O[2][4];
  #pragma unroll
  for (int fr = 0; fr < 2; fr++)
    #pragma unroll
    for (int fc = 0; fc < 4; fc++) O[fr][fc] = (f32x4)(0.f);
  float mrun[2][4], lrun[2][4];
  #pragma unroll
  for (int fr = 0; fr < 2; fr++)
    #pragma unroll
    for (int r = 0; r < 4; r++) { mrun[fr][r] = -1e30f; lrun[fr][r] = 0.f; }

  int srow = tid >> 2, sseg = tid & 3;
  int wb0 = srow * 128 + ((sseg * 32)      ^ ((srow & 7) << 4));
  int wb1 = srow * 128 + ((sseg * 32 + 16) ^ ((srow & 7) << 4));

  short8 k0r, k1r, v0r, v1r;
  {
    const unsigned short* ksrc = kg + srow * 64 + sseg * 16;
    const unsigned short* vsrc = vg + (size_t)srow * 2048 + sseg * 16;
    k0r = *(const short8*)(ksrc);     k1r = *(const short8*)(ksrc + 8);
    v0r = *(const short8*)(vsrc);     v1r = *(const short8*)(vsrc + 8);
    *(short8*)((char*)Kt[0] + wb0) = k0r;  *(short8*)((char*)Kt[0] + wb1) = k1r;
    *(short8*)((char*)Vt[0] + wb0) = v0r;  *(short8*)((char*)Vt[0] + wb1) = v1r;
  }

  for (int step = 0; step < 32; step++) {
    int buf = step & 1;
    __syncthreads();

    if (step + 1 < 32) {
      int kk = (step + 1) * 64;
      const unsigned short* ksrc = kg + (size_t)(kk + srow) * 64 + sseg * 16;
      const unsigned short* vsrc = vg + (size_t)srow * 2048 + kk + sseg * 16;
      k0r = *(const short8*)(ksrc);  k1r = *(const short8*)(ksrc + 8);
      v0r = *(const short8*)(vsrc);  v1r = *(const short8*)(vsrc + 8);
    }

    f32x4 S[2][4];
    #pragma unroll
    for (int fr = 0; fr < 2; fr++)
      #pragma unroll
      for (int fc = 0; fc < 4; fc++) S[fr][fc] = (f32x4)(0.f);
    #pragma unroll
    for (int ks = 0; ks < 2; ks++) {
      short8 kf[4];
      #pragma unroll
      for (int fc = 0; fc < 4; fc++) {
        int row = fc * 16 + l15;
        int byt = row * 128 + (((ks * 64) + l4 * 16) ^ ((row & 7) << 4));
        kf[fc] = *(const short8*)((char*)Kt[buf] + byt);
      }
      #pragma unroll
      for (int fr = 0; fr < 2; fr++)
        #pragma unroll
        for (int fc = 0; fc < 4; fc++)
          S[fr][fc] = mfma16(qf[fr][ks], kf[fc], S[fr][fc]);
    }

    #pragma unroll
    for (int fr = 0; fr < 2; fr++)
      #pragma unroll
      for (int r = 0; r < 4; r++) {
        float mx = fmaxf(fmaxf(S[fr][0][r], S[fr][1][r]), fmaxf(S[fr][2][r], S[fr][3][r]));
        mx = fmaxf(mx, __shfl_xor(mx, 1));
        mx = fmaxf(mx, __shfl_xor(mx, 2));
        mx = fmaxf(mx, __shfl_xor(mx, 4));
        mx = fmaxf(mx, __shfl_xor(mx, 8));
        float mold = mrun[fr][r];
        float mnew = fmaxf(mold, mx);
        float corr = exp2f(mold - mnew);
        mrun[fr][r] = mnew;
        float ls = lrun[fr][r] * corr;
        int row = fr * 16 + l4 * 4 + r;
        #pragma unroll
        for (int fc = 0; fc < 4; fc++) {
          float p = exp2f(S[fr][fc][r] - mnew);
          ls += p;
          int col = fc * 16 + l15;
          int byt = row * 128 + ((col * 2) ^ ((row & 7) << 4));
          *(unsigned short*)((char*)Pl[w] + byt) = f2bf(p);
          O[fr][fc][r] *= corr;
        }
        lrun[fr][r] = ls;
      }

    #pragma unroll
    for (int ks = 0; ks < 2; ks++) {
      short8 pf[2], vf[4];
      #pragma unroll
      for (int fr = 0; fr < 2; fr++) {
        int row = fr * 16 + l15;
        int byt = row * 128 + (((ks * 64) + l4 * 16) ^ ((row & 7) << 4));
        pf[fr] = *(const short8*)((char*)Pl[w] + byt);
      }
      #pragma unroll
      for (int fc = 0; fc < 4; fc++) {
        int row = fc * 16 + l15;
        int byt = row * 128 + (((ks * 64) + l4 * 16) ^ ((row & 7) << 4));
        vf[fc] = *(const short8*)((char*)Vt[buf] + byt);
      }
      #pragma unroll
      for (int fr = 0; fr < 2; fr++)
        #pragma unroll
        for (int fc = 0; fc < 4; fc++)
          O[fr][fc] = mfma16(pf[fr], vf[fc], O[fr][fc]);
    }

    if (step + 1 < 32) {
      int nb2 = buf ^ 1;
      *(short8*)((char*)Kt[nb2] + wb0) = k0r;  *(short8*)((char*)Kt[nb2] + wb1) = k1r;
      *(short8*)((char*)Vt[nb2] + wb0) = v0r;  *(short8*)((char*)Vt[nb2] + wb1) = v1r;
    }
  }

  float rinv[2][4];
  #pragma unroll
  for (int fr = 0; fr < 2; fr++)
    #pragma unroll
    for (int r = 0; r < 4; r++) {
      float ls = lrun[fr][r];
      ls += __shfl_xor(ls, 1);
      ls += __shfl_xor(ls, 2);
      ls += __shfl_xor(ls, 4);
      ls += __shfl_xor(ls, 8);
      rinv[fr][r] = 1.0f / ls;
    }

  float wc0[4], wc1[4];
  #pragma unroll
  for (int fc = 0; fc < 4; fc++) {
    wc0[fc] = Wrp[h * 64 + fc * 16 + l15];
    wc1[fc] = Wrp[1024 + h * 64 + fc * 16 + l15];
  }

  #pragma unroll
  for (int fr = 0; fr < 2; fr++)
    #pragma unroll
    for (int r = 0; r < 4; r++) {
      float a0 = 0.f, a1 = 0.f;
      #pragma unroll
      for (int fc = 0; fc < 4; fc++) {
        float o = O[fr][fc][r] * rinv[fr][r];
        a0 += o * wc0[fc];
        a1 += o * wc1[fc];
      }
      a0 += __shfl_xor(a0, 1); a0 += __shfl_xor(a0, 2);
      a0 += __shfl_xor(a0, 4); a0 += __shfl_xor(a0, 8);
      a1 += __shfl_xor(a1, 1); a1 += __shfl_xor(a1, 2);
      a1 += __shfl_xor(a1, 4); a1 += __shfl_xor(a1, 8);
      if (l15 == 0) {
        int qrow = q0 + fr * 16 + l4 * 4 + r;
        size_t base = ((size_t)(b * 16 + h) * 256 + qrow) * 2;
        part[base + 0] = a0;
        part[base + 1] = a1;
      }
    }
}

// ---------------------------------------------------------------------------
__global__ __launch_bounds__(256) void final_kernel(const float* __restrict__ part,
                                                    const float* __restrict__ br,
                                                    float* __restrict__ out) {
  int id = blockIdx.x * 256 + threadIdx.x;   // 8192
  int c = id & 1, q = (id >> 1) & 255, b = id >> 9;
  float s = br[c];
  #pragma unroll
  for (int hh = 0; hh < 16; hh++)
    s += part[(((size_t)(b * 16 + hh) * 256) + q) * 2 + c];
  out[id] = s;
}

// ---------------------------------------------------------------------------
extern "C" void kernel_launch(void* const* d_in, const int* in_sizes, int n_in,
                              void* d_out, int out_size, void* d_ws, size_t ws_size,
                              hipStream_t stream) {
  const float* h    = (const float*)d_in[0];
  const float* fcos = (const float*)d_in[1];
  const float* fsin = (const float*)d_in[2];
  const float* Wq   = (const float*)d_in[3];
  const float* Wk   = (const float*)d_in[4];
  const float* Wv   = (const float*)d_in[5];
  const float* Wo   = (const float*)d_in[6];
  const float* oq   = (const float*)d_in[7];
  const float* Wr   = (const float*)d_in[8];
  const float* br   = (const float*)d_in[9];
  float* out = (float*)d_out;

  char* ws = (char*)d_ws;
  unsigned short* kbuf = (unsigned short*)(ws);                 // 16 MB (B,KV,K,D) bf16
  unsigned short* vbuf = (unsigned short*)(ws + 16777216);      // 16 MB (B,KV,D,K) bf16
  float* qpart         = (float*)(ws + 33554432);               // 4 MB (4,256,1024)
  unsigned short* qbf  = (unsigned short*)(ws + 37748736);      // 0.5 MB (H,BIN,D)
  float* wpart         = (float*)(ws + 38273024);               // 128 KB
  float* Wrp           = (float*)(ws + 38404096);               // 8 KB
  float* apart         = (float*)(ws + 38412288);               // 512 KB (B,H,BIN,2)
  unsigned short* wqb  = (unsigned short*)(ws + 38936576);      // 2 MB (1024,1024)
  unsigned short* wkvb = (unsigned short*)(ws + 41033728);      // 1 MB (512,1024)

  cvtB_kernel<<<dim3(1536), dim3(256), 0, stream>>>(Wq, Wk, Wv, wqb, wkvb);
  wrp_partial<<<dim3(16), dim3(256), 0, stream>>>(Wr, Wo, wpart);
  wrp_reduce<<<dim3(8), dim3(256), 0, stream>>>(wpart, Wrp);
  gemm_q<<<dim3(64), dim3(256), 0, stream>>>(oq, wqb, qpart);
  rope_kernel<<<dim3(1024), dim3(256), 0, stream>>>(qpart, fcos, fsin, qbf);
  gemm_kv<<<dim3(1024), dim3(256), 0, stream>>>(h, wkvb, kbuf, vbuf);
  attn_kernel<<<dim3(512), dim3(256), 0, stream>>>(qbf, kbuf, vbuf, Wrp, apart);
  final_kernel<<<dim3(32), dim3(256), 0, stream>>>(apart, br, out);
}

// Round 6
// 199.923 us; speedup vs baseline: 1.5800x; 1.5800x over previous
//
#include <hip/hip_runtime.h>

typedef __attribute__((ext_vector_type(8))) short short8;
typedef __attribute__((ext_vector_type(4))) float f32x4;

#define DEV static __device__ __forceinline__

DEV unsigned short f2bf(float f) {
  unsigned int u = __float_as_uint(f);
  u += 0x7fff + ((u >> 16) & 1);   // RNE
  return (unsigned short)(u >> 16);
}

DEV unsigned int cvtpk(float lo, float hi) {   // packed f32x2 -> bf16x2 (RNE)
  unsigned int r;
  asm("v_cvt_pk_bf16_f32 %0, %1, %2" : "=v"(r) : "v"(lo), "v"(hi));
  return r;
}

DEV f32x4 mfma16(short8 a, short8 b, f32x4 c) {
  return __builtin_amdgcn_mfma_f32_16x16x32_bf16(a, b, c, 0, 0, 0);
}

DEV void gl_lds16(const void* g, void* l) {
  __builtin_amdgcn_global_load_lds((const __attribute__((address_space(1))) void*)g,
                                   (__attribute__((address_space(3))) void*)l, 16, 0, 0);
}

// ---------------------------------------------------------------------------
// Convert Wq / Wk / Wv fp32 -> bf16 (wqb 1024x1024; wkvb 512x1024, k then v)
// ---------------------------------------------------------------------------
__global__ __launch_bounds__(256) void cvtB_kernel(const float* __restrict__ Wq,
                                                   const float* __restrict__ Wk,
                                                   const float* __restrict__ Wv,
                                                   unsigned short* __restrict__ wqb,
                                                   unsigned short* __restrict__ wkvb) {
  int id = blockIdx.x * 256 + threadIdx.x;
  int e = id * 4;
  float4 v;
  unsigned short* d;
  if (e < 1048576)      { v = *(const float4*)(Wq + e);             d = wqb + e; }
  else if (e < 1310720) { v = *(const float4*)(Wk + (e - 1048576)); d = wkvb + (e - 1048576); }
  else                  { v = *(const float4*)(Wv + (e - 1310720)); d = wkvb + 262144 + (e - 1310720); }
  uint2 pk;
  pk.x = cvtpk(v.x, v.y);
  pk.y = cvtpk(v.z, v.w);
  *(uint2*)d = pk;
}

// ---------------------------------------------------------------------------
// Wrp = Wr @ Wo  (2 x 1024)
// ---------------------------------------------------------------------------
__global__ __launch_bounds__(256) void wrp_partial(const float* __restrict__ Wr,
                                                   const float* __restrict__ Wo,
                                                   float* __restrict__ part) {
  int blk = blockIdx.x;
  int tid = threadIdx.x;
  float a0[4] = {0.f,0.f,0.f,0.f};
  float a1[4] = {0.f,0.f,0.f,0.f};
  int e0 = blk * 64;
  for (int e = e0; e < e0 + 64; e++) {
    float w0 = Wr[e];
    float w1 = Wr[1024 + e];
    #pragma unroll
    for (int j4 = 0; j4 < 4; j4++) {
      float wo = Wo[(size_t)e * 1024 + j4 * 256 + tid];
      a0[j4] += w0 * wo;
      a1[j4] += w1 * wo;
    }
  }
  #pragma unroll
  for (int j4 = 0; j4 < 4; j4++) {
    part[blk * 2048 + 0    + j4 * 256 + tid] = a0[j4];
    part[blk * 2048 + 1024 + j4 * 256 + tid] = a1[j4];
  }
}

__global__ __launch_bounds__(256) void wrp_reduce(const float* __restrict__ part,
                                                  float* __restrict__ Wrp) {
  int id = blockIdx.x * 256 + threadIdx.x;
  float s = 0.f;
  #pragma unroll
  for (int blk = 0; blk < 16; blk++) s += part[blk * 2048 + id];
  Wrp[id] = s;
}

// ---------------------------------------------------------------------------
// KV projection: C = h(fp32, 32768x1024) @ Wkv(bf16, 512x1024)^T
// BM=64, BN=512 (full N -> h read ONCE; B panel 1MB is L2-resident),
// BK=32, 512 threads = 8 waves (2x4), 16 MFMA/wave/step, grid 512
// (2 blocks/CU, LDS 72KB). A: dense float4 (8 lanes/row = full lines)
// -> cvt_pk -> ds_write_b64. B: global_load_lds. LDS [rows][32]bf16,
// 64B rows: all b128 frag reads bank-conflict-free.
// Output: ok bf16 (B,KV,K,D), ov bf16 (B,KV,D,K) transposed.
// ---------------------------------------------------------------------------
__global__ __launch_bounds__(512, 4) void gemm_kv(const float* __restrict__ A,
                                                  const unsigned short* __restrict__ Bb,
                                                  unsigned short* __restrict__ ok,
                                                  unsigned short* __restrict__ ov) {
  __shared__ unsigned short Asl[2][2048];    // [64][32] bf16, 4KB each
  __shared__ unsigned short Bsl[2][16384];   // [512][32] bf16, 32KB each

  int bid = blockIdx.x;
  int m0 = bid * 64;

  int tid = threadIdx.x;
  int w = tid >> 6, l = tid & 63;
  int l4 = l >> 4, l15 = l & 15;
  int wm = w >> 2, wn = w & 3;

  // A staging: row = tid>>3 (0..63), 4 fp32 at (tid&7)*4
  int arow = tid >> 3;
  const float* ga = A + (size_t)(m0 + arow) * 1024 + (tid & 7) * 4;
  int awb = arow * 64 + (tid & 7) * 8;       // LDS byte offset (b64 write)

  // B staging: slot tid -> row tid>>2, k-chunk (tid&3)*8 ; 4 rounds of 128 rows
  const unsigned short* gb = Bb + (size_t)(tid >> 2) * 1024 + (tid & 3) * 8;
  int bdst = tid * 16;

  // fragment read offsets
  int aoff = (wm * 32 + l15) * 64 + l4 * 16;   // + i*1024
  int boff = (wn * 128 + l15) * 64 + l4 * 16;  // + j*1024

  f32x4 acc[2][8];
  #pragma unroll
  for (int i = 0; i < 2; i++)
    #pragma unroll
    for (int j = 0; j < 8; j++) acc[i][j] = (f32x4)(0.f);

  #define STAGEB(bufi, tt)                                                  \
    { const unsigned short* s0 = gb + (tt) * 32;                            \
      char* d0 = (char*)Bsl[bufi] + bdst;                                   \
      gl_lds16(s0,          d0);                                            \
      gl_lds16(s0 + 131072, d0 + 8192);                                     \
      gl_lds16(s0 + 262144, d0 + 16384);                                    \
      gl_lds16(s0 + 393216, d0 + 24576); }

  #define WRITEA(bufi, av)                                                  \
    { uint2 pk2;                                                            \
      pk2.x = cvtpk(av.x, av.y);                                            \
      pk2.y = cvtpk(av.z, av.w);                                            \
      *(uint2*)((char*)Asl[bufi] + awb) = pk2; }

  {
    float4 a0 = *(const float4*)(ga);
    STAGEB(0, 0);
    WRITEA(0, a0);
  }
  __syncthreads();

  for (int t = 0; t < 32; t++) {
    int buf = t & 1;
    float4 an;
    if (t + 1 < 32) {
      STAGEB(buf ^ 1, t + 1);
      an = *(const float4*)(ga + (t + 1) * 32);
    }

    short8 af[2];
    #pragma unroll
    for (int i = 0; i < 2; i++)
      af[i] = *(const short8*)((char*)Asl[buf] + aoff + i * 1024);
    #pragma unroll
    for (int j = 0; j < 8; j++) {
      short8 bf = *(const short8*)((char*)Bsl[buf] + boff + j * 1024);
      #pragma unroll
      for (int i = 0; i < 2; i++)
        acc[i][j] = mfma16(af[i], bf, acc[i][j]);
    }

    if (t + 1 < 32) WRITEA(buf ^ 1, an);
    __syncthreads();
  }
  #undef STAGEB
  #undef WRITEA

  // epilogue: n = wn*128 + j*16 + l15, m = m0 + wm*32 + i*16 + l4*4 + r
  #pragma unroll
  for (int i = 0; i < 2; i++)
    #pragma unroll
    for (int j = 0; j < 8; j++) {
      int n = wn * 128 + j * 16 + l15;
      int kvv = n >> 6, d = n & 63;
      #pragma unroll
      for (int r = 0; r < 4; r++) {
        int m = m0 + wm * 32 + i * 16 + l4 * 4 + r;
        int bb = m >> 11, kk = m & 2047;
        unsigned short val = f2bf(acc[i][j][r]);
        if (kvv < 4)
          ok[((size_t)(bb * 4 + kvv) * 2048 + kk) * 64 + d] = val;           // (B,KV,K,D)
        else
          ov[((size_t)(bb * 4 + (kvv - 4)) * 64 + d) * 2048 + kk] = val;     // (B,KV,D,K)
      }
    }
}

// ---------------------------------------------------------------------------
// q projection GEMM (small): C = oq @ Wq^T, 128x128 tile, BK=32, 4-way K-split
// ---------------------------------------------------------------------------
__global__ __launch_bounds__(256) void gemm_q(const float* __restrict__ A,
                                              const unsigned short* __restrict__ Bb,
                                              float* __restrict__ of) {
  __shared__ unsigned short Asm[2][4096];
  __shared__ unsigned short Bsm[2][4096];

  int bid = blockIdx.x;
  int ksplit = bid >> 4;
  int m0 = ((bid >> 3) & 1) * 128;
  int n0 = (bid & 7) * 128;
  int t0 = ksplit * 8;
  constexpr int nt = 8;

  int tid = threadIdx.x;
  int w = tid >> 6, l = tid & 63;
  int l4 = l >> 4, l15 = l & 15;
  int wm = w >> 1, wn = w & 1;

  int ra = w * 32 + (l >> 1);
  int rx = (l >> 2) & 3;
  const float* ga = A + (size_t)(m0 + ra) * 1024 + t0 * 32 + (l & 1) * 16;
  int pw0 = (2 * (l & 1) + 0) ^ rx;
  int pw1 = (2 * (l & 1) + 1) ^ rx;
  int awb0 = ra * 64 + pw0 * 16;
  int awb1 = ra * 64 + pw1 * 16;

  int rb = w * 32 + (l >> 2);
  int cb = ((l & 3) ^ ((l >> 3) & 3)) * 8;
  const unsigned short* gb = Bb + (size_t)(n0 + rb) * 1024 + t0 * 32 + cb;

  int qsw = l4 ^ ((l15 >> 1) & 3);
  int arb = (wm * 64 + l15) * 64 + qsw * 16;
  int brb = (wn * 64 + l15) * 64 + qsw * 16;

  f32x4 acc[4][4];
  #pragma unroll
  for (int i = 0; i < 4; i++)
    #pragma unroll
    for (int j = 0; j < 4; j++) acc[i][j] = (f32x4)(0.f);

  float4 fa0, fa1, fa2, fa3;

  #define LOADA(tt)                                                        \
    { const float* gA = ga + (tt) * 32;                                    \
      fa0 = *(const float4*)(gA);                                          \
      fa1 = *(const float4*)(gA + 4);                                      \
      fa2 = *(const float4*)(gA + 8);                                      \
      fa3 = *(const float4*)(gA + 12); }

  #define WRITEA(bufi)                                                     \
    { union { short8 s; unsigned int u[4]; } t0u, t1u;                     \
      t0u.u[0] = cvtpk(fa0.x, fa0.y); t0u.u[1] = cvtpk(fa0.z, fa0.w);      \
      t0u.u[2] = cvtpk(fa1.x, fa1.y); t0u.u[3] = cvtpk(fa1.z, fa1.w);      \
      t1u.u[0] = cvtpk(fa2.x, fa2.y); t1u.u[1] = cvtpk(fa2.z, fa2.w);      \
      t1u.u[2] = cvtpk(fa3.x, fa3.y); t1u.u[3] = cvtpk(fa3.z, fa3.w);      \
      *(short8*)((char*)Asm[bufi] + awb0) = t0u.s;                         \
      *(short8*)((char*)Asm[bufi] + awb1) = t1u.s; }

  #define STAGEB(bufi, tt)                                                 \
    { char* lb = (char*)Bsm[bufi] + w * 2048;                              \
      const unsigned short* gB = gb + (tt) * 32;                           \
      gl_lds16(gB, lb);                                                    \
      gl_lds16(gB + 16384, lb + 1024); }

  LOADA(0);
  STAGEB(0, 0);
  WRITEA(0);
  __syncthreads();

  for (int t = 0; t < nt; t++) {
    int buf = t & 1;
    if (t + 1 < nt) {
      LOADA(t + 1);
      STAGEB(buf ^ 1, t + 1);
    }
    short8 af[4], bfg[4];
    #pragma unroll
    for (int i = 0; i < 4; i++)
      af[i] = *(const short8*)((char*)Asm[buf] + arb + i * 1024);
    #pragma unroll
    for (int j = 0; j < 4; j++)
      bfg[j] = *(const short8*)((char*)Bsm[buf] + brb + j * 1024);
    #pragma unroll
    for (int i = 0; i < 4; i++)
      #pragma unroll
      for (int j = 0; j < 4; j++)
        acc[i][j] = mfma16(af[i], bfg[j], acc[i][j]);
    if (t + 1 < nt) WRITEA(buf ^ 1);
    __syncthreads();
  }
  #undef LOADA
  #undef WRITEA
  #undef STAGEB

  float* o = of + (size_t)ksplit * 262144;
  #pragma unroll
  for (int i = 0; i < 4; i++)
    #pragma unroll
    for (int j = 0; j < 4; j++) {
      int n = n0 + wn * 64 + j * 16 + l15;
      #pragma unroll
      for (int r = 0; r < 4; r++) {
        int m = m0 + wm * 64 + i * 16 + l4 * 4 + r;
        o[(size_t)m * 1024 + n] = acc[i][j][r];
      }
    }
}

// ---------------------------------------------------------------------------
// Sum 4 K-split partials + RoPE + scale, write bf16 as (H, BIN, D)
// ---------------------------------------------------------------------------
__global__ __launch_bounds__(256) void rope_kernel(const float* __restrict__ qp,
                                                   const float* __restrict__ cosb,
                                                   const float* __restrict__ sinb,
                                                   unsigned short* __restrict__ qb) {
  int id = blockIdx.x * 256 + threadIdx.x;   // 262144
  int qrow = id >> 10, hd = id & 1023, hh = hd >> 6, d = hd & 63;
  int od = hh * 64 + ((d < 32) ? d + 32 : d - 32);
  float v = 0.f, o = 0.f;
  #pragma unroll
  for (int s4 = 0; s4 < 4; s4++) {
    v += qp[s4 * 262144 + qrow * 1024 + hd];
    o += qp[s4 * 262144 + qrow * 1024 + od];
  }
  if (d < 32) o = -o;
  float c = cosb[qrow * 64 + d];
  float s = sinb[qrow * 64 + d];
  float outv = (v * c + o * s) * 0.18033688011112042f;  // 0.125 * log2(e)
  qb[((size_t)hh * 256 + qrow) * 64 + d] = f2bf(outv);
}

// ---------------------------------------------------------------------------
// Flash attention, one block per (b, h, q-half). 4 waves x 32 q-rows.
// Block-index decode co-locates the 8 blocks sharing one (b,kvh) K/V on the
// same XCD (bid&7 = (b*4+kvh)&7) so K/V re-reads hit that XCD's L2.
// ---------------------------------------------------------------------------
__global__ __launch_bounds__(256) void attn_kernel(const unsigned short* __restrict__ qb,
                                                   const unsigned short* __restrict__ kb,
                                                   const unsigned short* __restrict__ vb,
                                                   const float* __restrict__ Wrp,
                                                   float* __restrict__ part) {
  __shared__ unsigned short Kt[2][4096];
  __shared__ unsigned short Vt[2][4096];
  __shared__ unsigned short Pl[4][2048];

  int bid = blockIdx.x;
  int x = bid & 7, g = bid >> 3;
  int hlow = (g >> 1) & 3, qh = g & 1;
  int t8 = (g >> 3) * 8 + x;          // b*4 + kvh
  int b = t8 >> 2, kvh = t8 & 3;
  int h = kvh * 4 + hlow;

  int tid = threadIdx.x;
  int w = tid >> 6, l = tid & 63;
  int l4 = l >> 4, l15 = l & 15;
  int q0 = qh * 128 + w * 32;

  const unsigned short* kg = kb + (size_t)(b * 4 + kvh) * 2048 * 64;
  const unsigned short* vg = vb + (size_t)(b * 4 + kvh) * 64 * 2048;

  short8 qf[2][2];
  #pragma unroll
  for (int fr = 0; fr < 2; fr++)
    #pragma unroll
    for (int ks = 0; ks < 2; ks++)
      qf[fr][ks] = *(const short8*)&qb[((size_t)h * 256 + q0 + fr * 16 + l15) * 64 + ks * 32 + l4 * 8];

  f32x4 O[2][4];
  #pragma unroll
  for (int fr = 0; fr < 2; fr++)
    #pragma unroll
    for (int fc = 0; fc < 4; fc++) O[fr][fc] = (f32x4)(0.f);
  float mrun[2][4], lrun[2][4];
  #pragma unroll
  for (int fr = 0; fr < 2; fr++)
    #pragma unroll
    for (int r = 0; r < 4; r++) { mrun[fr][r] = -1e30f; lrun[fr][r] = 0.f; }

  int srow = tid >> 2, sseg = tid & 3;
  int wb0 = srow * 128 + ((sseg * 32)      ^ ((srow & 7) << 4));
  int wb1 = srow * 128 + ((sseg * 32 + 16) ^ ((srow & 7) << 4));

  short8 k0r, k1r, v0r, v1r;
  {
    const unsigned short* ksrc = kg + srow * 64 + sseg * 16;
    const unsigned short* vsrc = vg + (size_t)srow * 2048 + sseg * 16;
    k0r = *(const short8*)(ksrc);     k1r = *(const short8*)(ksrc + 8);
    v0r = *(const short8*)(vsrc);     v1r = *(const short8*)(vsrc + 8);
    *(short8*)((char*)Kt[0] + wb0) = k0r;  *(short8*)((char*)Kt[0] + wb1) = k1r;
    *(short8*)((char*)Vt[0] + wb0) = v0r;  *(short8*)((char*)Vt[0] + wb1) = v1r;
  }

  for (int step = 0; step < 32; step++) {
    int buf = step & 1;
    __syncthreads();

    if (step + 1 < 32) {
      int kk = (step + 1) * 64;
      const unsigned short* ksrc = kg + (size_t)(kk + srow) * 64 + sseg * 16;
      const unsigned short* vsrc = vg + (size_t)srow * 2048 + kk + sseg * 16;
      k0r = *(const short8*)(ksrc);  k1r = *(const short8*)(ksrc + 8);
      v0r = *(const short8*)(vsrc);  v1r = *(const short8*)(vsrc + 8);
    }

    f32x4 S[2][4];
    #pragma unroll
    for (int fr = 0; fr < 2; fr++)
      #pragma unroll
      for (int fc = 0; fc < 4; fc++) S[fr][fc] = (f32x4)(0.f);
    #pragma unroll
    for (int ks = 0; ks < 2; ks++) {
      short8 kf[4];
      #pragma unroll
      for (int fc = 0; fc < 4; fc++) {
        int row = fc * 16 + l15;
        int byt = row * 128 + (((ks * 64) + l4 * 16) ^ ((row & 7) << 4));
        kf[fc] = *(const short8*)((char*)Kt[buf] + byt);
      }
      #pragma unroll
      for (int fr = 0; fr < 2; fr++)
        #pragma unroll
        for (int fc = 0; fc < 4; fc++)
          S[fr][fc] = mfma16(qf[fr][ks], kf[fc], S[fr][fc]);
    }

    #pragma unroll
    for (int fr = 0; fr < 2; fr++)
      #pragma unroll
      for (int r = 0; r < 4; r++) {
        float mx = fmaxf(fmaxf(S[fr][0][r], S[fr][1][r]), fmaxf(S[fr][2][r], S[fr][3][r]));
        mx = fmaxf(mx, __shfl_xor(mx, 1));
        mx = fmaxf(mx, __shfl_xor(mx, 2));
        mx = fmaxf(mx, __shfl_xor(mx, 4));
        mx = fmaxf(mx, __shfl_xor(mx, 8));
        float mold = mrun[fr][r];
        float mnew = fmaxf(mold, mx);
        float corr = exp2f(mold - mnew);
        mrun[fr][r] = mnew;
        float ls = lrun[fr][r] * corr;
        int row = fr * 16 + l4 * 4 + r;
        #pragma unroll
        for (int fc = 0; fc < 4; fc++) {
          float p = exp2f(S[fr][fc][r] - mnew);
          ls += p;
          int col = fc * 16 + l15;
          int byt = row * 128 + ((col * 2) ^ ((row & 7) << 4));
          *(unsigned short*)((char*)Pl[w] + byt) = f2bf(p);
          O[fr][fc][r] *= corr;
        }
        lrun[fr][r] = ls;
      }

    #pragma unroll
    for (int ks = 0; ks < 2; ks++) {
      short8 pf[2], vf[4];
      #pragma unroll
      for (int fr = 0; fr < 2; fr++) {
        int row = fr * 16 + l15;
        int byt = row * 128 + (((ks * 64) + l4 * 16) ^ ((row & 7) << 4));
        pf[fr] = *(const short8*)((char*)Pl[w] + byt);
      }
      #pragma unroll
      for (int fc = 0; fc < 4; fc++) {
        int row = fc * 16 + l15;
        int byt = row * 128 + (((ks * 64) + l4 * 16) ^ ((row & 7) << 4));
        vf[fc] = *(const short8*)((char*)Vt[buf] + byt);
      }
      #pragma unroll
      for (int fr = 0; fr < 2; fr++)
        #pragma unroll
        for (int fc = 0; fc < 4; fc++)
          O[fr][fc] = mfma16(pf[fr], vf[fc], O[fr][fc]);
    }

    if (step + 1 < 32) {
      int nb2 = buf ^ 1;
      *(short8*)((char*)Kt[nb2] + wb0) = k0r;  *(short8*)((char*)Kt[nb2] + wb1) = k1r;
      *(short8*)((char*)Vt[nb2] + wb0) = v0r;  *(short8*)((char*)Vt[nb2] + wb1) = v1r;
    }
  }

  float rinv[2][4];
  #pragma unroll
  for (int fr = 0; fr < 2; fr++)
    #pragma unroll
    for (int r = 0; r < 4; r++) {
      float ls = lrun[fr][r];
      ls += __shfl_xor(ls, 1);
      ls += __shfl_xor(ls, 2);
      ls += __shfl_xor(ls, 4);
      ls += __shfl_xor(ls, 8);
      rinv[fr][r] = 1.0f / ls;
    }

  float wc0[4], wc1[4];
  #pragma unroll
  for (int fc = 0; fc < 4; fc++) {
    wc0[fc] = Wrp[h * 64 + fc * 16 + l15];
    wc1[fc] = Wrp[1024 + h * 64 + fc * 16 + l15];
  }

  #pragma unroll
  for (int fr = 0; fr < 2; fr++)
    #pragma unroll
    for (int r = 0; r < 4; r++) {
      float a0 = 0.f, a1 = 0.f;
      #pragma unroll
      for (int fc = 0; fc < 4; fc++) {
        float o = O[fr][fc][r] * rinv[fr][r];
        a0 += o * wc0[fc];
        a1 += o * wc1[fc];
      }
      a0 += __shfl_xor(a0, 1); a0 += __shfl_xor(a0, 2);
      a0 += __shfl_xor(a0, 4); a0 += __shfl_xor(a0, 8);
      a1 += __shfl_xor(a1, 1); a1 += __shfl_xor(a1, 2);
      a1 += __shfl_xor(a1, 4); a1 += __shfl_xor(a1, 8);
      if (l15 == 0) {
        int qrow = q0 + fr * 16 + l4 * 4 + r;
        size_t base = ((size_t)(b * 16 + h) * 256 + qrow) * 2;
        part[base + 0] = a0;
        part[base + 1] = a1;
      }
    }
}

// ---------------------------------------------------------------------------
__global__ __launch_bounds__(256) void final_kernel(const float* __restrict__ part,
                                                    const float* __restrict__ br,
                                                    float* __restrict__ out) {
  int id = blockIdx.x * 256 + threadIdx.x;   // 8192
  int c = id & 1, q = (id >> 1) & 255, b = id >> 9;
  float s = br[c];
  #pragma unroll
  for (int hh = 0; hh < 16; hh++)
    s += part[(((size_t)(b * 16 + hh) * 256) + q) * 2 + c];
  out[id] = s;
}

// ---------------------------------------------------------------------------
extern "C" void kernel_launch(void* const* d_in, const int* in_sizes, int n_in,
                              void* d_out, int out_size, void* d_ws, size_t ws_size,
                              hipStream_t stream) {
  const float* h    = (const float*)d_in[0];
  const float* fcos = (const float*)d_in[1];
  const float* fsin = (const float*)d_in[2];
  const float* Wq   = (const float*)d_in[3];
  const float* Wk   = (const float*)d_in[4];
  const float* Wv   = (const float*)d_in[5];
  const float* Wo   = (const float*)d_in[6];
  const float* oq   = (const float*)d_in[7];
  const float* Wr   = (const float*)d_in[8];
  const float* br   = (const float*)d_in[9];
  float* out = (float*)d_out;

  char* ws = (char*)d_ws;
  unsigned short* kbuf = (unsigned short*)(ws);                 // 16 MB (B,KV,K,D) bf16
  unsigned short* vbuf = (unsigned short*)(ws + 16777216);      // 16 MB (B,KV,D,K) bf16
  float* qpart         = (float*)(ws + 33554432);               // 4 MB (4,256,1024)
  unsigned short* qbf  = (unsigned short*)(ws + 37748736);      // 0.5 MB (H,BIN,D)
  float* wpart         = (float*)(ws + 38273024);               // 128 KB
  float* Wrp           = (float*)(ws + 38404096);               // 8 KB
  float* apart         = (float*)(ws + 38412288);               // 512 KB (B,H,BIN,2)
  unsigned short* wqb  = (unsigned short*)(ws + 38936576);      // 2 MB (1024,1024)
  unsigned short* wkvb = (unsigned short*)(ws + 41033728);      // 1 MB (512,1024)

  cvtB_kernel<<<dim3(1536), dim3(256), 0, stream>>>(Wq, Wk, Wv, wqb, wkvb);
  wrp_partial<<<dim3(16), dim3(256), 0, stream>>>(Wr, Wo, wpart);
  wrp_reduce<<<dim3(8), dim3(256), 0, stream>>>(wpart, Wrp);
  gemm_q<<<dim3(64), dim3(256), 0, stream>>>(oq, wqb, qpart);
  rope_kernel<<<dim3(1024), dim3(256), 0, stream>>>(qpart, fcos, fsin, qbf);
  gemm_kv<<<dim3(512), dim3(512), 0, stream>>>(h, wkvb, kbuf, vbuf);
  attn_kernel<<<dim3(512), dim3(256), 0, stream>>>(qbf, kbuf, vbuf, Wrp, apart);
  final_kernel<<<dim3(32), dim3(256), 0, stream>>>(apart, br, out);
}

// Round 7
// 174.276 us; speedup vs baseline: 1.8125x; 1.1472x over previous
//
#include <hip/hip_runtime.h>

typedef __attribute__((ext_vector_type(8))) short short8;
typedef __attribute__((ext_vector_type(4))) float f32x4;
typedef __attribute__((ext_vector_type(16))) float f32x16;

#define DEV static __device__ __forceinline__

DEV unsigned short f2bf(float f) {
  unsigned int u = __float_as_uint(f);
  u += 0x7fff + ((u >> 16) & 1);   // RNE
  return (unsigned short)(u >> 16);
}

DEV unsigned int cvtpk(float lo, float hi) {   // packed f32x2 -> bf16x2 (RNE)
  unsigned int r;
  asm("v_cvt_pk_bf16_f32 %0, %1, %2" : "=v"(r) : "v"(lo), "v"(hi));
  return r;
}

DEV f32x4 mfma16(short8 a, short8 b, f32x4 c) {
  return __builtin_amdgcn_mfma_f32_16x16x32_bf16(a, b, c, 0, 0, 0);
}

DEV f32x16 mfma32(short8 a, short8 b, f32x16 c) {
  return __builtin_amdgcn_mfma_f32_32x32x16_bf16(a, b, c, 0, 0, 0);
}

DEV void gl_lds16(const void* g, void* l) {
  __builtin_amdgcn_global_load_lds((const __attribute__((address_space(1))) void*)g,
                                   (__attribute__((address_space(3))) void*)l, 16, 0, 0);
}

// ---------------------------------------------------------------------------
// Convert Wq / Wk / Wv fp32 -> bf16 (wqb 1024x1024; wkvb 512x1024, k then v)
// ---------------------------------------------------------------------------
__global__ __launch_bounds__(256) void cvtB_kernel(const float* __restrict__ Wq,
                                                   const float* __restrict__ Wk,
                                                   const float* __restrict__ Wv,
                                                   unsigned short* __restrict__ wqb,
                                                   unsigned short* __restrict__ wkvb) {
  int id = blockIdx.x * 256 + threadIdx.x;
  int e = id * 4;
  float4 v;
  unsigned short* d;
  if (e < 1048576)      { v = *(const float4*)(Wq + e);             d = wqb + e; }
  else if (e < 1310720) { v = *(const float4*)(Wk + (e - 1048576)); d = wkvb + (e - 1048576); }
  else                  { v = *(const float4*)(Wv + (e - 1310720)); d = wkvb + 262144 + (e - 1310720); }
  uint2 pk;
  pk.x = cvtpk(v.x, v.y);
  pk.y = cvtpk(v.z, v.w);
  *(uint2*)d = pk;
}

// ---------------------------------------------------------------------------
// Wrp = Wr @ Wo  (2 x 1024)
// ---------------------------------------------------------------------------
__global__ __launch_bounds__(256) void wrp_partial(const float* __restrict__ Wr,
                                                   const float* __restrict__ Wo,
                                                   float* __restrict__ part) {
  int blk = blockIdx.x;
  int tid = threadIdx.x;
  float a0[4] = {0.f,0.f,0.f,0.f};
  float a1[4] = {0.f,0.f,0.f,0.f};
  int e0 = blk * 64;
  for (int e = e0; e < e0 + 64; e++) {
    float w0 = Wr[e];
    float w1 = Wr[1024 + e];
    #pragma unroll
    for (int j4 = 0; j4 < 4; j4++) {
      float wo = Wo[(size_t)e * 1024 + j4 * 256 + tid];
      a0[j4] += w0 * wo;
      a1[j4] += w1 * wo;
    }
  }
  #pragma unroll
  for (int j4 = 0; j4 < 4; j4++) {
    part[blk * 2048 + 0    + j4 * 256 + tid] = a0[j4];
    part[blk * 2048 + 1024 + j4 * 256 + tid] = a1[j4];
  }
}

__global__ __launch_bounds__(256) void wrp_reduce(const float* __restrict__ part,
                                                  float* __restrict__ Wrp) {
  int id = blockIdx.x * 256 + threadIdx.x;
  float s = 0.f;
  #pragma unroll
  for (int blk = 0; blk < 16; blk++) s += part[blk * 2048 + id];
  Wrp[id] = s;
}

// ---------------------------------------------------------------------------
// KV projection: C = h(fp32, 32768x1024) @ Wkv(bf16, 512x1024)^T   (unchanged)
// ---------------------------------------------------------------------------
__global__ __launch_bounds__(512, 4) void gemm_kv(const float* __restrict__ A,
                                                  const unsigned short* __restrict__ Bb,
                                                  unsigned short* __restrict__ ok,
                                                  unsigned short* __restrict__ ov) {
  __shared__ unsigned short Asl[2][2048];    // [64][32] bf16, 4KB each
  __shared__ unsigned short Bsl[2][16384];   // [512][32] bf16, 32KB each

  int bid = blockIdx.x;
  int m0 = bid * 64;

  int tid = threadIdx.x;
  int w = tid >> 6, l = tid & 63;
  int l4 = l >> 4, l15 = l & 15;
  int wm = w >> 2, wn = w & 3;

  int arow = tid >> 3;
  const float* ga = A + (size_t)(m0 + arow) * 1024 + (tid & 7) * 4;
  int awb = arow * 64 + (tid & 7) * 8;

  const unsigned short* gb = Bb + (size_t)(tid >> 2) * 1024 + (tid & 3) * 8;
  int bdst = tid * 16;

  int aoff = (wm * 32 + l15) * 64 + l4 * 16;
  int boff = (wn * 128 + l15) * 64 + l4 * 16;

  f32x4 acc[2][8];
  #pragma unroll
  for (int i = 0; i < 2; i++)
    #pragma unroll
    for (int j = 0; j < 8; j++) acc[i][j] = (f32x4)(0.f);

  #define STAGEB(bufi, tt)                                                  \
    { const unsigned short* s0 = gb + (tt) * 32;                            \
      char* d0 = (char*)Bsl[bufi] + bdst;                                   \
      gl_lds16(s0,          d0);                                            \
      gl_lds16(s0 + 131072, d0 + 8192);                                     \
      gl_lds16(s0 + 262144, d0 + 16384);                                    \
      gl_lds16(s0 + 393216, d0 + 24576); }

  #define WRITEA(bufi, av)                                                  \
    { uint2 pk2;                                                            \
      pk2.x = cvtpk(av.x, av.y);                                            \
      pk2.y = cvtpk(av.z, av.w);                                            \
      *(uint2*)((char*)Asl[bufi] + awb) = pk2; }

  {
    float4 a0 = *(const float4*)(ga);
    STAGEB(0, 0);
    WRITEA(0, a0);
  }
  __syncthreads();

  for (int t = 0; t < 32; t++) {
    int buf = t & 1;
    float4 an;
    if (t + 1 < 32) {
      STAGEB(buf ^ 1, t + 1);
      an = *(const float4*)(ga + (t + 1) * 32);
    }

    short8 af[2];
    #pragma unroll
    for (int i = 0; i < 2; i++)
      af[i] = *(const short8*)((char*)Asl[buf] + aoff + i * 1024);
    #pragma unroll
    for (int j = 0; j < 8; j++) {
      short8 bf = *(const short8*)((char*)Bsl[buf] + boff + j * 1024);
      #pragma unroll
      for (int i = 0; i < 2; i++)
        acc[i][j] = mfma16(af[i], bf, acc[i][j]);
    }

    if (t + 1 < 32) WRITEA(buf ^ 1, an);
    __syncthreads();
  }
  #undef STAGEB
  #undef WRITEA

  #pragma unroll
  for (int i = 0; i < 2; i++)
    #pragma unroll
    for (int j = 0; j < 8; j++) {
      int n = wn * 128 + j * 16 + l15;
      int kvv = n >> 6, d = n & 63;
      #pragma unroll
      for (int r = 0; r < 4; r++) {
        int m = m0 + wm * 32 + i * 16 + l4 * 4 + r;
        int bb = m >> 11, kk = m & 2047;
        unsigned short val = f2bf(acc[i][j][r]);
        if (kvv < 4)
          ok[((size_t)(bb * 4 + kvv) * 2048 + kk) * 64 + d] = val;           // (B,KV,K,D)
        else
          ov[((size_t)(bb * 4 + (kvv - 4)) * 64 + d) * 2048 + kk] = val;     // (B,KV,D,K)
      }
    }
}

// ---------------------------------------------------------------------------
// q projection GEMM (small): C = oq @ Wq^T, 128x128 tile, BK=32, 4-way K-split
// ---------------------------------------------------------------------------
__global__ __launch_bounds__(256) void gemm_q(const float* __restrict__ A,
                                              const unsigned short* __restrict__ Bb,
                                              float* __restrict__ of) {
  __shared__ unsigned short Asm[2][4096];
  __shared__ unsigned short Bsm[2][4096];

  int bid = blockIdx.x;
  int ksplit = bid >> 4;
  int m0 = ((bid >> 3) & 1) * 128;
  int n0 = (bid & 7) * 128;
  int t0 = ksplit * 8;
  constexpr int nt = 8;

  int tid = threadIdx.x;
  int w = tid >> 6, l = tid & 63;
  int l4 = l >> 4, l15 = l & 15;
  int wm = w >> 1, wn = w & 1;

  int ra = w * 32 + (l >> 1);
  int rx = (l >> 2) & 3;
  const float* ga = A + (size_t)(m0 + ra) * 1024 + t0 * 32 + (l & 1) * 16;
  int pw0 = (2 * (l & 1) + 0) ^ rx;
  int pw1 = (2 * (l & 1) + 1) ^ rx;
  int awb0 = ra * 64 + pw0 * 16;
  int awb1 = ra * 64 + pw1 * 16;

  int rb = w * 32 + (l >> 2);
  int cb = ((l & 3) ^ ((l >> 3) & 3)) * 8;
  const unsigned short* gb = Bb + (size_t)(n0 + rb) * 1024 + t0 * 32 + cb;

  int qsw = l4 ^ ((l15 >> 1) & 3);
  int arb = (wm * 64 + l15) * 64 + qsw * 16;
  int brb = (wn * 64 + l15) * 64 + qsw * 16;

  f32x4 acc[4][4];
  #pragma unroll
  for (int i = 0; i < 4; i++)
    #pragma unroll
    for (int j = 0; j < 4; j++) acc[i][j] = (f32x4)(0.f);

  float4 fa0, fa1, fa2, fa3;

  #define LOADA(tt)                                                        \
    { const float* gA = ga + (tt) * 32;                                    \
      fa0 = *(const float4*)(gA);                                          \
      fa1 = *(const float4*)(gA + 4);                                      \
      fa2 = *(const float4*)(gA + 8);                                      \
      fa3 = *(const float4*)(gA + 12); }

  #define WRITEA(bufi)                                                     \
    { union { short8 s; unsigned int u[4]; } t0u, t1u;                     \
      t0u.u[0] = cvtpk(fa0.x, fa0.y); t0u.u[1] = cvtpk(fa0.z, fa0.w);      \
      t0u.u[2] = cvtpk(fa1.x, fa1.y); t0u.u[3] = cvtpk(fa1.z, fa1.w);      \
      t1u.u[0] = cvtpk(fa2.x, fa2.y); t1u.u[1] = cvtpk(fa2.z, fa2.w);      \
      t1u.u[2] = cvtpk(fa3.x, fa3.y); t1u.u[3] = cvtpk(fa3.z, fa3.w);      \
      *(short8*)((char*)Asm[bufi] + awb0) = t0u.s;                         \
      *(short8*)((char*)Asm[bufi] + awb1) = t1u.s; }

  #define STAGEB(bufi, tt)                                                 \
    { char* lb = (char*)Bsm[bufi] + w * 2048;                              \
      const unsigned short* gB = gb + (tt) * 32;                           \
      gl_lds16(gB, lb);                                                    \
      gl_lds16(gB + 16384, lb + 1024); }

  LOADA(0);
  STAGEB(0, 0);
  WRITEA(0);
  __syncthreads();

  for (int t = 0; t < nt; t++) {
    int buf = t & 1;
    if (t + 1 < nt) {
      LOADA(t + 1);
      STAGEB(buf ^ 1, t + 1);
    }
    short8 af[4], bfg[4];
    #pragma unroll
    for (int i = 0; i < 4; i++)
      af[i] = *(const short8*)((char*)Asm[buf] + arb + i * 1024);
    #pragma unroll
    for (int j = 0; j < 4; j++)
      bfg[j] = *(const short8*)((char*)Bsm[buf] + brb + j * 1024);
    #pragma unroll
    for (int i = 0; i < 4; i++)
      #pragma unroll
      for (int j = 0; j < 4; j++)
        acc[i][j] = mfma16(af[i], bfg[j], acc[i][j]);
    if (t + 1 < nt) WRITEA(buf ^ 1);
    __syncthreads();
  }
  #undef LOADA
  #undef WRITEA
  #undef STAGEB

  float* o = of + (size_t)ksplit * 262144;
  #pragma unroll
  for (int i = 0; i < 4; i++)
    #pragma unroll
    for (int j = 0; j < 4; j++) {
      int n = n0 + wn * 64 + j * 16 + l15;
      #pragma unroll
      for (int r = 0; r < 4; r++) {
        int m = m0 + wm * 64 + i * 16 + l4 * 4 + r;
        o[(size_t)m * 1024 + n] = acc[i][j][r];
      }
    }
}

// ---------------------------------------------------------------------------
// Sum 4 K-split partials + RoPE + scale, write bf16 as (H, BIN, D)
// ---------------------------------------------------------------------------
__global__ __launch_bounds__(256) void rope_kernel(const float* __restrict__ qp,
                                                   const float* __restrict__ cosb,
                                                   const float* __restrict__ sinb,
                                                   unsigned short* __restrict__ qb) {
  int id = blockIdx.x * 256 + threadIdx.x;   // 262144
  int qrow = id >> 10, hd = id & 1023, hh = hd >> 6, d = hd & 63;
  int od = hh * 64 + ((d < 32) ? d + 32 : d - 32);
  float v = 0.f, o = 0.f;
  #pragma unroll
  for (int s4 = 0; s4 < 4; s4++) {
    v += qp[s4 * 262144 + qrow * 1024 + hd];
    o += qp[s4 * 262144 + qrow * 1024 + od];
  }
  if (d < 32) o = -o;
  float c = cosb[qrow * 64 + d];
  float s = sinb[qrow * 64 + d];
  float outv = (v * c + o * s) * 0.18033688011112042f;  // 0.125 * log2(e)
  qb[((size_t)hh * 256 + qrow) * 64 + d] = f2bf(outv);
}

// ---------------------------------------------------------------------------
// Flash attention v2 — swapped-operand 32x32 MFMA (T12 structure).
// 512 blocks = (b,kvh) x hl x qh, co-located per (b,kvh) on one XCD.
// 4 warps x 32 q-rows (qh half). KVBLK=32, 64 steps.
// S^T = mfma32(K, Q): lane owns q = lane&31; keys (reg&3)+8*(reg>>2)+4*(l>>5).
// Softmax fully in-register (1 shfl_xor(32)/step); P -> bf16 via cvt_pk +
// v_permlane32_swap (no LDS round-trip). O^T = mfma32(V^T, P): O, m, l all
// lane-local. K / V^T tiles via global_load_lds, pre-swizzled source.
// Epilogue folds Wrp -> part (B,H,BIN,2).
// ---------------------------------------------------------------------------
__global__ __launch_bounds__(256) void attn_kernel(const unsigned short* __restrict__ qb,
                                                   const unsigned short* __restrict__ kb,
                                                   const unsigned short* __restrict__ vb,
                                                   const float* __restrict__ Wrp,
                                                   float* __restrict__ part) {
  __shared__ unsigned short Kt[2][2048];   // [32 keys][64 d] swizzled, 4KB
  __shared__ unsigned short Vt[2][2048];   // [32 d .. 64 d? no: [64 d][32 k]] see below

  // NOTE: Kt tile = 32 keys x 64 d (rows=key, 128B/row).
  //       Vt tile = 64 d x 32 keys (rows=d, 64B/row) -> 2048 u16 = 4KB.

  int bid = blockIdx.x;
  int x = bid & 7, mid = (bid >> 3) & 7, top = bid >> 6;
  int g = mid * 8 + x;                 // b*4 + kvh
  int b = g >> 2, kvh = g & 3;
  int hl = top >> 1, qh = top & 1;
  int h = kvh * 4 + hl;

  int tid = threadIdx.x;
  int w = tid >> 6, l = tid & 63;
  int q31 = l & 31, L = l >> 5;
  int qg = qh * 128 + w * 32 + q31;    // global q row

  const unsigned short* kg = kb + (size_t)(b * 4 + kvh) * 2048 * 64;
  const unsigned short* vg = vb + (size_t)(b * 4 + kvh) * 64 * 2048;

  // Q b-frags: qf[c] = Q[qg][c*16 + L*8 .. +8], c = d-chunk
  short8 qf[4];
  #pragma unroll
  for (int c = 0; c < 4; c++)
    qf[c] = *(const short8*)&qb[((size_t)h * 256 + qg) * 64 + c * 16 + L * 8];

  f32x16 Ot[2];                        // O^T: [d-block], col q=l&31, row d
  Ot[0] = (f32x16)(0.f); Ot[1] = (f32x16)(0.f);
  float m = -1e30f, lsum = 0.f;

  // ---- staging: K tile rows=key(32) 128B; V^T tile rows=d(64) 64B ----
  // K: 256 threads x 16B = 4KB = full tile. row=tid>>3, slot=tid&7 (8 slots)
  int ksrow = tid >> 3, kslot = tid & 7;
  const unsigned short* ksrc = kg + (size_t)ksrow * 64 + ((kslot ^ (ksrow & 7)) * 8);
  // V^T: row=tid>>2 (64 rows), slot=tid&3 (4 slots of 16B)
  int vsrow = tid >> 2, vslot = tid & 3;
  const unsigned short* vsrc = vg + (size_t)vsrow * 2048 + ((vslot ^ (vsrow & 3)) * 8);

  #define STAGE(bufi, tt)                                                    \
    { gl_lds16(ksrc + (size_t)(tt) * 2048, (char*)Kt[bufi] + tid * 16);      \
      gl_lds16(vsrc + (tt) * 32,           (char*)Vt[bufi] + tid * 16); }

  STAGE(0, 0);
  __syncthreads();

  for (int t = 0; t < 64; t++) {
    int buf = t & 1;
    if (t + 1 < 64) STAGE(buf ^ 1, t + 1);

    // ---- S^T = K · Q^T  (32 keys x 32 q) ----
    f32x16 st = (f32x16)(0.f);
    #pragma unroll
    for (int c = 0; c < 4; c++) {
      int row = q31;                                   // key row
      int byt = row * 128 + (((c * 2 + L) ^ (row & 7)) * 16);
      short8 kf = *(const short8*)((char*)Kt[buf] + byt);
      st = mfma32(kf, qf[c], st);
    }

    // ---- softmax (lane-local row; keys (reg&3)+8*(reg>>2)+4L) ----
    float mx = fmaxf(fmaxf(fmaxf(st[0], st[1]), fmaxf(st[2], st[3])),
                     fmaxf(fmaxf(st[4], st[5]), fmaxf(st[6], st[7])));
    float mx2 = fmaxf(fmaxf(fmaxf(st[8], st[9]), fmaxf(st[10], st[11])),
                      fmaxf(fmaxf(st[12], st[13]), fmaxf(st[14], st[15])));
    mx = fmaxf(mx, mx2);
    mx = fmaxf(mx, __shfl_xor(mx, 32));                // cross-half: full row max

    if (!__all(mx <= m + 8.f)) {                       // defer-max (T13)
      float mnew = fmaxf(m, mx);
      float corr = exp2f(m - mnew);
      lsum *= corr;
      #pragma unroll
      for (int db = 0; db < 2; db++)
        #pragma unroll
        for (int r = 0; r < 16; r++) Ot[db][r] *= corr;
      m = mnew;
    }

    float p[16];
    float ls = 0.f;
    #pragma unroll
    for (int r = 0; r < 16; r++) {
      p[r] = exp2f(st[r] - m);
      ls += p[r];
    }
    lsum += ls;                                        // own-half partial sum

    // ---- P -> bf16 b-frags via cvt_pk + permlane32_swap ----
    unsigned int pw[2][4];
    #pragma unroll
    for (int kc = 0; kc < 2; kc++) {
      unsigned int A0 = cvtpk(p[kc * 8 + 0], p[kc * 8 + 1]);
      unsigned int A1 = cvtpk(p[kc * 8 + 2], p[kc * 8 + 3]);
      unsigned int B0 = cvtpk(p[kc * 8 + 4], p[kc * 8 + 5]);
      unsigned int B1 = cvtpk(p[kc * 8 + 6], p[kc * 8 + 7]);
      asm volatile("v_permlane32_swap_b32 %0, %1" : "+v"(A0), "+v"(B0));
      asm volatile("v_permlane32_swap_b32 %0, %1" : "+v"(A1), "+v"(B1));
      pw[kc][0] = A0; pw[kc][1] = A1; pw[kc][2] = B0; pw[kc][3] = B1;
    }

    // ---- O^T += V^T · P^T ----
    #pragma unroll
    for (int db = 0; db < 2; db++) {
      int drow = db * 32 + q31;
      #pragma unroll
      for (int kc = 0; kc < 2; kc++) {
        int byt = drow * 64 + (((kc * 2 + L) ^ (drow & 3)) * 16);
        short8 vf = *(const short8*)((char*)Vt[buf] + byt);
        short8 pf;
        {
          union { short8 s; unsigned int u[4]; } uu;
          uu.u[0] = pw[kc][0]; uu.u[1] = pw[kc][1];
          uu.u[2] = pw[kc][2]; uu.u[3] = pw[kc][3];
          pf = uu.s;
        }
        Ot[db] = mfma32(vf, pf, Ot[db]);
      }
    }

    __syncthreads();
  }
  #undef STAGE

  // ---- epilogue: normalize + fold Wrp, all lane-local ----
  lsum += __shfl_xor(lsum, 32);
  float rinv = 1.0f / lsum;

  float a0 = 0.f, a1 = 0.f;
  #pragma unroll
  for (int db = 0; db < 2; db++)
    #pragma unroll
    for (int rq = 0; rq < 4; rq++) {
      int dbase = db * 32 + rq * 8 + L * 4;
      float4 w0v = *(const float4*)(Wrp + h * 64 + dbase);
      float4 w1v = *(const float4*)(Wrp + 1024 + h * 64 + dbase);
      #pragma unroll
      for (int j = 0; j < 4; j++) {
        float o = Ot[db][rq * 4 + j] * rinv;
        a0 += o * ((const float*)&w0v)[j];
        a1 += o * ((const float*)&w1v)[j];
      }
    }
  a0 += __shfl_xor(a0, 32);
  a1 += __shfl_xor(a1, 32);

  if (L == 0) {
    size_t base = ((size_t)(b * 16 + h) * 256 + qg) * 2;
    float2 r2; r2.x = a0; r2.y = a1;
    *(float2*)&part[base] = r2;
  }
}

// ---------------------------------------------------------------------------
__global__ __launch_bounds__(256) void final_kernel(const float* __restrict__ part,
                                                    const float* __restrict__ br,
                                                    float* __restrict__ out) {
  int id = blockIdx.x * 256 + threadIdx.x;   // 8192
  int c = id & 1, q = (id >> 1) & 255, b = id >> 9;
  float s = br[c];
  #pragma unroll
  for (int hh = 0; hh < 16; hh++)
    s += part[(((size_t)(b * 16 + hh) * 256) + q) * 2 + c];
  out[id] = s;
}

// ---------------------------------------------------------------------------
extern "C" void kernel_launch(void* const* d_in, const int* in_sizes, int n_in,
                              void* d_out, int out_size, void* d_ws, size_t ws_size,
                              hipStream_t stream) {
  const float* h    = (const float*)d_in[0];
  const float* fcos = (const float*)d_in[1];
  const float* fsin = (const float*)d_in[2];
  const float* Wq   = (const float*)d_in[3];
  const float* Wk   = (const float*)d_in[4];
  const float* Wv   = (const float*)d_in[5];
  const float* Wo   = (const float*)d_in[6];
  const float* oq   = (const float*)d_in[7];
  const float* Wr   = (const float*)d_in[8];
  const float* br   = (const float*)d_in[9];
  float* out = (float*)d_out;

  char* ws = (char*)d_ws;
  unsigned short* kbuf = (unsigned short*)(ws);                 // 16 MB (B,KV,K,D) bf16
  unsigned short* vbuf = (unsigned short*)(ws + 16777216);      // 16 MB (B,KV,D,K) bf16
  float* qpart         = (float*)(ws + 33554432);               // 4 MB (4,256,1024)
  unsigned short* qbf  = (unsigned short*)(ws + 37748736);      // 0.5 MB (H,BIN,D)
  float* wpart         = (float*)(ws + 38273024);               // 128 KB
  float* Wrp           = (float*)(ws + 38404096);               // 8 KB
  float* apart         = (float*)(ws + 38412288);               // 512 KB (B,H,BIN,2)
  unsigned short* wqb  = (unsigned short*)(ws + 38936576);      // 2 MB (1024,1024)
  unsigned short* wkvb = (unsigned short*)(ws + 41033728);      // 1 MB (512,1024)

  cvtB_kernel<<<dim3(1536), dim3(256), 0, stream>>>(Wq, Wk, Wv, wqb, wkvb);
  wrp_partial<<<dim3(16), dim3(256), 0, stream>>>(Wr, Wo, wpart);
  wrp_reduce<<<dim3(8), dim3(256), 0, stream>>>(wpart, Wrp);
  gemm_q<<<dim3(64), dim3(256), 0, stream>>>(oq, wqb, qpart);
  rope_kernel<<<dim3(1024), dim3(256), 0, stream>>>(qpart, fcos, fsin, qbf);
  gemm_kv<<<dim3(512), dim3(512), 0, stream>>>(h, wkvb, kbuf, vbuf);
  attn_kernel<<<dim3(512), dim3(256), 0, stream>>>(qbf, kbuf, vbuf, Wrp, apart);
  final_kernel<<<dim3(32), dim3(256), 0, stream>>>(apart, br, out);
}